// Round 8
// baseline (1299.894 us; speedup 1.0000x reference)
//
#include <hip/hip_runtime.h>
#include <hip/hip_bf16.h>
#include <stdint.h>

#define N_NODES 50000
#define N_EDGES 320000
#define MP 50048   // padded node rows = 391 * 128

typedef __hip_bfloat16 bf16_t;
typedef __attribute__((ext_vector_type(8))) short short8;
typedef __attribute__((ext_vector_type(4))) float floatx4;

// ---------------- edge_index dtype detection (int32 vs int64) ----------------
__global__ void detect_kernel(const int* __restrict__ ei, int* __restrict__ flag) {
    int tid = threadIdx.x;                  // 64 threads
    int v = ei[2 * tid + 1];
    unsigned long long b = __ballot(v != 0);
    if (tid == 0) *flag = (b == 0ull) ? 1 : 0;   // 1 => int64
}

__device__ __forceinline__ int load_edge(const int* ei, int row, int e, int is64) {
    long pos = (long)row * N_EDGES + e;
    return is64 ? ei[2 * pos] : ei[pos];   // little-endian low word
}

// ---------------- fat preprocessing kernel: count + cast_x + cast_w ----------
#define CB 1250     // count blocks    = N_EDGES/256
#define XB 25024    // cast_x blocks   = MP*512/4/256
#define WB 14976    // cast_w blocks   = 3,833,856/256

__global__ __launch_bounds__(256)
void preproc_kernel(const int* __restrict__ ei, const int* __restrict__ flag,
                    int* __restrict__ counts,
                    const float* __restrict__ x, bf16_t* __restrict__ xb,
                    const float* __restrict__ W1, const float* __restrict__ W2,
                    const float* __restrict__ W3, const float* __restrict__ W4,
                    const float* __restrict__ W5,
                    bf16_t* __restrict__ wt1, bf16_t* __restrict__ wt2,
                    bf16_t* __restrict__ wt3, bf16_t* __restrict__ wt4,
                    bf16_t* __restrict__ wt5) {
    int bid = blockIdx.x;
    int tid = threadIdx.x;
    if (bid < CB) {
        int e = bid * 256 + tid;
        if (e < N_EDGES) {
            int d = load_edge(ei, 1, e, *flag);
            atomicAdd(&counts[d], 1);
        }
    } else if (bid < CB + XB) {
        long idx = ((long)(bid - CB) * 256 + tid) * 4;
        union { bf16_t h[4]; uint2 u; } o;
        long row = idx >> 9;
        if (row < N_NODES) {
            float4 v = *(const float4*)(x + idx);
            o.h[0] = __float2bfloat16(v.x);
            o.h[1] = __float2bfloat16(v.y);
            o.h[2] = __float2bfloat16(v.z);
            o.h[3] = __float2bfloat16(v.w);
        } else {
            o.u = make_uint2(0u, 0u);
        }
        *(uint2*)(xb + idx) = o.u;
    } else {
        long idx = (long)(bid - CB - XB) * 256 + tid;
        const float* Ws; bf16_t* Wd; int K, Nn; long off;
        if      (idx < 1048576) { Ws = W1; Wd = wt1; K = 512;  Nn = 2048; off = 0; }
        else if (idx < 3145728) { Ws = W2; Wd = wt2; K = 2048; Nn = 1024; off = 1048576; }
        else if (idx < 3670016) { Ws = W3; Wd = wt3; K = 1024; Nn = 512;  off = 3145728; }
        else if (idx < 3801088) { Ws = W4; Wd = wt4; K = 512;  Nn = 256;  off = 3670016; }
        else if (idx < 3833856) { Ws = W5; Wd = wt5; K = 256;  Nn = 128;  off = 3801088; }
        else return;
        long i = idx - off;
        int nn = (int)(i & (Nn - 1));
        int kk = (int)(i >> __builtin_ctz(Nn));
        Wd[(size_t)nn * K + kk] = __float2bfloat16(Ws[i]);
    }
}

// ---------------- CSR build ----------------
__global__ __launch_bounds__(1024)
void scan_kernel(const int* __restrict__ counts, int* __restrict__ rowptr,
                 int* __restrict__ cursor, float* __restrict__ dinv,
                 float* __restrict__ selfw) {
    __shared__ int wsum[16];
    __shared__ int base_s;
    int tid  = threadIdx.x;
    int lane = tid & 63;
    int wv   = tid >> 6;
    if (tid == 0) base_s = 0;
    __syncthreads();
    for (int start = 0; start < N_NODES; start += 1024) {
        int i = start + tid;
        int v = (i < N_NODES) ? counts[i] : 0;
        int s = v;
#pragma unroll
        for (int off = 1; off < 64; off <<= 1) {
            int t = __shfl_up(s, off, 64);
            if (lane >= off) s += t;
        }
        if (lane == 63) wsum[wv] = s;
        __syncthreads();
        if (wv == 0 && lane < 16) {
            int t = wsum[lane];
#pragma unroll
            for (int off = 1; off < 16; off <<= 1) {
                int u = __shfl_up(t, off, 64);
                if (lane >= off) t += u;
            }
            wsum[lane] = t;
        }
        __syncthreads();
        int wbase = (wv == 0) ? 0 : wsum[wv - 1];
        int incl  = s + wbase;
        int base  = base_s;
        if (i < N_NODES) {
            int excl = base + incl - v;
            rowptr[i] = excl;
            cursor[i] = excl;
            float di = rsqrtf((float)v + 1.0f);   // deg includes self-loop
            dinv[i] = di;
            selfw[i] = di * di;
        }
        __syncthreads();
        if (tid == 1023) base_s = base + incl;
        __syncthreads();
    }
    if (tid == 0) rowptr[N_NODES] = N_EDGES;
}

__global__ void fill_kernel(const int* __restrict__ ei, const int* __restrict__ flag,
                            int* __restrict__ cursor, const float* __restrict__ dinv,
                            int* __restrict__ esrc, float* __restrict__ ewt) {
    int e = blockIdx.x * 256 + threadIdx.x;
    if (e < N_EDGES) {
        int is64 = *flag;
        int s = load_edge(ei, 0, e, is64);
        int d = load_edge(ei, 1, e, is64);
        int p = atomicAdd(&cursor[d], 1);
        esrc[p] = s;
        ewt[p]  = dinv[s] * dinv[d];
    }
}

// ---------------- GEMM (producer-consumer): C[MP][Nn] = A[MP][K] @ Wt[Nn][K]^T
// 384 threads: waves 0-3 compute the 128x128 tile (identical fragment math /
// epilogue to the verified R5-R7 kernel), waves 4-5 are dedicated producers.
// 2 LDS stages x 32KB. NO __syncthreads in the K-loop: producers issue
// global_load_lds, s_waitcnt vmcnt(0) (stalls only themselves), release-store
// ready[]; consumers acquire-spin then ds_read+MFMA, signal done[]. This is
// the documented path past the m97 barrier-drain plateau (prefetch stays in
// flight across the sync point).
#define BM 128
#define BN 128
#define BK 64
#define NSTAGE 2

__device__ __forceinline__ void stage16(const bf16_t* g, bf16_t* l) {
    __builtin_amdgcn_global_load_lds(
        (const __attribute__((address_space(1))) void*)g,
        (__attribute__((address_space(3))) void*)l, 16, 0, 0);
}

__global__ __launch_bounds__(384)
void gemm_bf16(const bf16_t* __restrict__ A, const bf16_t* __restrict__ Bt,
               bf16_t* __restrict__ C, int K, int Nn,
               const float* __restrict__ bias, int relu, int nx, int ny) {
    int id   = blockIdx.x;
    int xcd  = id & 7;
    int slot = id >> 3;
    int y    = (slot / nx) * 8 + xcd;
    int xt   = slot % nx;
    if (y >= ny) return;

    __shared__ __align__(16) bf16_t lds[NSTAGE * 16384];   // 2 x (A 16KB + B 16KB)
    __shared__ int ready[NSTAGE];
    __shared__ int done[NSTAGE];

    int tid  = threadIdx.x;
    int lane = tid & 63;
    int wave = tid >> 6;
    long bm0 = (long)y * BM;
    long bn0 = (long)xt * BN;
    int iters = K >> 6;

    if (tid < NSTAGE) { ready[tid] = 0; done[tid] = 0; }
    __syncthreads();   // only barrier in the kernel

    if (wave >= 4) {
        // ---------------- producer: wave 4 -> stage 0, wave 5 -> stage 1 ----
        int p = wave - 4;
        bf16_t* sa = lds + p * 16384;
        bf16_t* sb = sa + 8192;
        for (int it = p; it < iters; it += NSTAGE) {
            int u = it >> 1;   // prior uses of this stage
            while (__atomic_load_n(&done[p], __ATOMIC_ACQUIRE) < 4 * u)
                __builtin_amdgcn_s_sleep(1);
            int k0 = it << 6;
#pragma unroll
            for (int j = 0; j < 16; ++j) {
                int f   = j * 64 + lane;          // 16B slot in 16KB tile
                int row = f >> 3;                 // 8 slots per 128B row
                int blk = ((f & 7) ^ (row & 7)) * 8;   // XOR swizzle (global side)
                stage16(A  + (bm0 + row) * (long)K + k0 + blk, sa + f * 8);
                stage16(Bt + (bn0 + row) * (long)K + k0 + blk, sb + f * 8);
            }
            asm volatile("s_waitcnt vmcnt(0)" ::: "memory");   // only this wave stalls
            __atomic_store_n(&ready[p], it + 1, __ATOMIC_RELEASE);
        }
        return;
    }

    // ---------------- consumer: waves 0-3, identical tile math to R5-R7 ----
    int m15  = lane & 15;
    int quad = lane >> 4;
    int wm = (wave & 1) * 64;
    int wn = (wave >> 1) * 64;

    floatx4 acc[4][4] = {};

    int fx   = lane & 7;
    int blk0 = ((0 + quad) ^ fx) * 8;     // kk = 0
    int blk1 = ((4 + quad) ^ fx) * 8;     // kk = 32
    int rowA = (wm + m15) * BK;
    int rowB = (wn + m15) * BK;

    for (int it = 0; it < iters; ++it) {
        int s = it & 1;
        while (__atomic_load_n(&ready[s], __ATOMIC_ACQUIRE) < it + 1)
            __builtin_amdgcn_s_sleep(1);
        const bf16_t* sa = lds + s * 16384;
        const bf16_t* sb = sa + 8192;
#pragma unroll
        for (int kk = 0; kk < 2; ++kk) {
            int blk = kk ? blk1 : blk0;
            short8 af[4], bfr[4];
#pragma unroll
            for (int i = 0; i < 4; ++i)
                af[i] = *(const short8*)(&sa[rowA + i * (16 * BK) + blk]);
#pragma unroll
            for (int j = 0; j < 4; ++j)
                bfr[j] = *(const short8*)(&sb[rowB + j * (16 * BK) + blk]);
#pragma unroll
            for (int i = 0; i < 4; ++i)
#pragma unroll
                for (int j = 0; j < 4; ++j)
                    acc[i][j] = __builtin_amdgcn_mfma_f32_16x16x32_bf16(af[i], bfr[j], acc[i][j], 0, 0, 0);
        }
        if (lane == 0)
            __atomic_fetch_add(&done[s], 1, __ATOMIC_RELEASE);  // lgkm-fenced: ds_reads done
    }

    // epilogue: D row = quad*4 + r, col = lane&15 (verified m89/m91 layout)
#pragma unroll
    for (int i = 0; i < 4; ++i) {
#pragma unroll
        for (int j = 0; j < 4; ++j) {
            long row0 = bm0 + wm + i * 16 + quad * 4;
            long col  = bn0 + wn + j * 16 + m15;
            float bv = bias ? bias[col] : 0.f;
#pragma unroll
            for (int r = 0; r < 4; ++r) {
                float v = acc[i][j][r] + bv;
                if (relu) v = fmaxf(v, 0.f);
                C[(row0 + r) * (long)Nn + col] = __float2bfloat16(v);
            }
        }
    }
}

// ---------------- aggregation (unchanged from R7) ----------------
__device__ __forceinline__ void unpack8(uint4 v, float* f) {
    uint32_t u[4] = {v.x, v.y, v.z, v.w};
#pragma unroll
    for (int i = 0; i < 4; ++i) {
        f[2 * i]     = __uint_as_float(u[i] << 16);
        f[2 * i + 1] = __uint_as_float(u[i] & 0xffff0000u);
    }
}

__global__ __launch_bounds__(256)
void agg_kernel(const bf16_t* __restrict__ hW, const int* __restrict__ rowptr,
                const int* __restrict__ esrc, const float* __restrict__ ewt,
                const float* __restrict__ selfw,
                const float* __restrict__ bias, bf16_t* __restrict__ outb,
                float* __restrict__ outf, int Nn, int chunks, int npw, int nsh,
                int relu, int rows) {
    int wave = threadIdx.x >> 6;
    int lane = threadIdx.x & 63;
    long unit = (long)blockIdx.x * 4 + wave;
    int n, c0;
    if (npw > 1) {
        int l8 = lane * 8;
        n  = (int)(unit * npw + (l8 >> nsh));
        c0 = l8 & (Nn - 1);
    } else {
        n  = (int)(unit / chunks);
        c0 = (int)(unit % chunks) * 512 + lane * 8;
    }
    if (n >= rows || c0 >= Nn) return;

    if (n >= N_NODES) {                         // zero pad rows (bf16 outputs)
        if (outb) *(uint4*)(outb + (size_t)n * Nn + c0) = make_uint4(0, 0, 0, 0);
        return;
    }

    int r0 = rowptr[n], r1 = rowptr[n + 1];
    float acc[8] = {};

    for (int e = r0; e < r1; e += 4) {
        int e1 = (e + 1 < r1) ? e + 1 : e;
        int e2 = (e + 2 < r1) ? e + 2 : e;
        int e3 = (e + 3 < r1) ? e + 3 : e;
        int s0 = esrc[e], s1 = esrc[e1], s2 = esrc[e2], s3 = esrc[e3];
        float w0 = ewt[e];
        float w1 = (e + 1 < r1) ? ewt[e1] : 0.f;
        float w2 = (e + 2 < r1) ? ewt[e2] : 0.f;
        float w3 = (e + 3 < r1) ? ewt[e3] : 0.f;
        uint4 v0 = *(const uint4*)(hW + (size_t)s0 * Nn + c0);
        uint4 v1 = *(const uint4*)(hW + (size_t)s1 * Nn + c0);
        uint4 v2 = *(const uint4*)(hW + (size_t)s2 * Nn + c0);
        uint4 v3 = *(const uint4*)(hW + (size_t)s3 * Nn + c0);
        float f0[8], f1[8], f2[8], f3[8];
        unpack8(v0, f0); unpack8(v1, f1); unpack8(v2, f2); unpack8(v3, f3);
#pragma unroll
        for (int j = 0; j < 8; ++j)
            acc[j] += f0[j] * w0 + f1[j] * w1 + f2[j] * w2 + f3[j] * w3;
    }

    {   // self-loop
        uint4 v = *(const uint4*)(hW + (size_t)n * Nn + c0);
        float fv[8]; unpack8(v, fv);
        float w = selfw[n];
#pragma unroll
        for (int j = 0; j < 8; ++j) acc[j] += fv[j] * w;
    }
    if (bias) {
#pragma unroll
        for (int j = 0; j < 8; ++j) acc[j] += bias[c0 + j];
    }
    if (relu) {
#pragma unroll
        for (int j = 0; j < 8; ++j) acc[j] = fmaxf(acc[j], 0.f);
    }
    if (outf) {
        *(float4*)(outf + (size_t)n * Nn + c0)     = make_float4(acc[0], acc[1], acc[2], acc[3]);
        *(float4*)(outf + (size_t)n * Nn + c0 + 4) = make_float4(acc[4], acc[5], acc[6], acc[7]);
    } else {
        union { bf16_t h[8]; uint4 u; } o;
#pragma unroll
        for (int j = 0; j < 8; ++j) o.h[j] = __float2bfloat16(acc[j]);
        *(uint4*)(outb + (size_t)n * Nn + c0) = o.u;
    }
}

// ---------------- driver ----------------
extern "C" void kernel_launch(void* const* d_in, const int* in_sizes, int n_in,
                              void* d_out, int out_size, void* d_ws, size_t ws_size,
                              hipStream_t stream) {
    (void)in_sizes; (void)n_in; (void)out_size; (void)ws_size;
    const float* x  = (const float*)d_in[0];
    const int*   ei = (const int*)d_in[1];
    const float* W[5] = {(const float*)d_in[2], (const float*)d_in[4], (const float*)d_in[6],
                         (const float*)d_in[8], (const float*)d_in[10]};
    const float* B[5] = {(const float*)d_in[3], (const float*)d_in[5], (const float*)d_in[7],
                         (const float*)d_in[9], (const float*)d_in[11]};
    static const int dims[6] = {512, 2048, 1024, 512, 256, 128};

    // ---- arena (peak ~320 MB) ----
    const size_t SZ_A = (size_t)MP * 512 * 2;
    const size_t SZ_B = (size_t)MP * 512 * 2;
    const size_t SZ_C = (size_t)MP * 2048 * 2;
    char* base = (char*)d_ws;
    bf16_t* regA = (bf16_t*)base;
    bf16_t* regB = (bf16_t*)(base + SZ_A);
    bf16_t* regC = (bf16_t*)(base + SZ_A + SZ_B);
    char* p = base + SZ_A + SZ_B + SZ_C;
    auto take = [&](size_t bytes) { char* r = p; p += (bytes + 255) & ~(size_t)255; return r; };
    bf16_t* wt[5];
    for (int i = 0; i < 5; ++i) wt[i] = (bf16_t*)take((size_t)dims[i] * dims[i + 1] * 2);
    int*   counts = (int*)take((size_t)N_NODES * 4);
    int*   rowptr = (int*)take((size_t)(N_NODES + 1) * 4);
    int*   cursor = (int*)take((size_t)N_NODES * 4);
    int*   esrc   = (int*)take((size_t)N_EDGES * 4);
    float* ewt    = (float*)take((size_t)N_EDGES * 4);
    float* dinv   = (float*)take((size_t)N_NODES * 4);
    float* selfw  = (float*)take((size_t)N_NODES * 4);
    int*   eflag  = (int*)take(256);

    // ---- preprocessing ----
    detect_kernel<<<1, 64, 0, stream>>>(ei, eflag);
    hipMemsetAsync(counts, 0, (size_t)N_NODES * 4, stream);
    bf16_t* xb = regA;
    preproc_kernel<<<CB + XB + WB, 256, 0, stream>>>(ei, eflag, counts, x, xb,
                                                     W[0], W[1], W[2], W[3], W[4],
                                                     wt[0], wt[1], wt[2], wt[3], wt[4]);
    scan_kernel<<<1, 1024, 0, stream>>>(counts, rowptr, cursor, dinv, selfw);
    fill_kernel<<<(N_EDGES + 255) / 256, 256, 0, stream>>>(ei, eflag, cursor, dinv, esrc, ewt);

    auto launch_gemm = [&](const bf16_t* a, const bf16_t* bt, bf16_t* c,
                           int K, int Nn, const float* bias, int relu) {
        int nx = Nn / BN;
        int ny = MP / BM;                       // 391
        int blocks = nx * (((ny + 7) / 8) * 8); // pad panel groups to 8 XCDs
        gemm_bf16<<<blocks, 384, 0, stream>>>(a, bt, c, K, Nn, bias, relu, nx, ny);
    };

    auto launch_agg = [&](const bf16_t* hw, const float* bias, bf16_t* outb,
                          float* outf, int Nn, int relu, int rows) {
        int chunks = Nn > 512 ? Nn / 512 : 1;
        int npw    = Nn < 512 ? 512 / Nn : 1;
        int nsh    = 31 - __builtin_clz(Nn);
        long units = (long)((rows + npw - 1) / npw) * chunks;
        int blocks = (int)((units + 3) / 4);
        agg_kernel<<<blocks, 256, 0, stream>>>(hw, rowptr, esrc, ewt, selfw, bias,
                                               outb, outf, Nn, chunks, npw, nsh, relu, rows);
    };

    // ---- layer 1: g1 = A_hat x ; h1 = relu(g1 @ W1 + b1) ----
    bf16_t* g1 = regB;
    bf16_t* h1 = regC;
    launch_agg(xb, nullptr, g1, nullptr, 512, 0, MP);
    launch_gemm(g1, wt[0], h1, 512, 2048, B[0], 1);

    // ---- layers 2..5 ----
    // buffer schedule: hw2->A+B, h2->C, hw3->A, h3->B, hw4->A, h4->B, hw5->A
    bf16_t* hwbuf[4] = {regA, regA, regA, regA};
    bf16_t* hbuf[3]  = {regC, regB, regB};
    const bf16_t* hin = h1;
    for (int l = 1; l < 5; ++l) {
        int K = dims[l], Nn = dims[l + 1];
        bf16_t* hw = hwbuf[l - 1];
        launch_gemm(hin, wt[l], hw, K, Nn, nullptr, 0);
        if (l < 4) {
            bf16_t* hn = hbuf[l - 1];
            launch_agg(hw, B[l], hn, nullptr, Nn, 1, MP);
            hin = hn;
        } else {
            launch_agg(hw, B[l], nullptr, (float*)d_out, Nn, 0, N_NODES);
        }
    }
}

// Round 9
// 1064.759 us; speedup vs baseline: 1.2208x; 1.2208x over previous
//
#include <hip/hip_runtime.h>
#include <hip/hip_bf16.h>
#include <stdint.h>

#define N_NODES 50000
#define N_EDGES 320000
#define MP 50048   // padded node rows = 391 * 128

typedef __hip_bfloat16 bf16_t;
typedef __attribute__((ext_vector_type(8))) short short8;
typedef __attribute__((ext_vector_type(4))) float floatx4;

// ---------------- edge_index dtype detection (int32 vs int64) ----------------
__global__ void detect_kernel(const int* __restrict__ ei, int* __restrict__ flag) {
    int tid = threadIdx.x;                  // 64 threads
    int v = ei[2 * tid + 1];
    unsigned long long b = __ballot(v != 0);
    if (tid == 0) *flag = (b == 0ull) ? 1 : 0;   // 1 => int64
}

__device__ __forceinline__ int load_edge(const int* ei, int row, int e, int is64) {
    long pos = (long)row * N_EDGES + e;
    return is64 ? ei[2 * pos] : ei[pos];   // little-endian low word
}

// ---------------- fat preprocessing kernel: count + cast_x + cast_w ----------
#define CB 1250     // count blocks    = N_EDGES/256
#define XB 25024    // cast_x blocks   = MP*512/4/256
#define WB 14976    // cast_w blocks   = 3,833,856/256

__global__ __launch_bounds__(256)
void preproc_kernel(const int* __restrict__ ei, const int* __restrict__ flag,
                    int* __restrict__ counts,
                    const float* __restrict__ x, bf16_t* __restrict__ xb,
                    const float* __restrict__ W1, const float* __restrict__ W2,
                    const float* __restrict__ W3, const float* __restrict__ W4,
                    const float* __restrict__ W5,
                    bf16_t* __restrict__ wt1, bf16_t* __restrict__ wt2,
                    bf16_t* __restrict__ wt3, bf16_t* __restrict__ wt4,
                    bf16_t* __restrict__ wt5) {
    int bid = blockIdx.x;
    int tid = threadIdx.x;
    if (bid < CB) {
        int e = bid * 256 + tid;
        if (e < N_EDGES) {
            int d = load_edge(ei, 1, e, *flag);
            atomicAdd(&counts[d], 1);
        }
    } else if (bid < CB + XB) {
        long idx = ((long)(bid - CB) * 256 + tid) * 4;
        union { bf16_t h[4]; uint2 u; } o;
        long row = idx >> 9;
        if (row < N_NODES) {
            float4 v = *(const float4*)(x + idx);
            o.h[0] = __float2bfloat16(v.x);
            o.h[1] = __float2bfloat16(v.y);
            o.h[2] = __float2bfloat16(v.z);
            o.h[3] = __float2bfloat16(v.w);
        } else {
            o.u = make_uint2(0u, 0u);
        }
        *(uint2*)(xb + idx) = o.u;
    } else {
        long idx = (long)(bid - CB - XB) * 256 + tid;
        const float* Ws; bf16_t* Wd; int K, Nn; long off;
        if      (idx < 1048576) { Ws = W1; Wd = wt1; K = 512;  Nn = 2048; off = 0; }
        else if (idx < 3145728) { Ws = W2; Wd = wt2; K = 2048; Nn = 1024; off = 1048576; }
        else if (idx < 3670016) { Ws = W3; Wd = wt3; K = 1024; Nn = 512;  off = 3145728; }
        else if (idx < 3801088) { Ws = W4; Wd = wt4; K = 512;  Nn = 256;  off = 3670016; }
        else if (idx < 3833856) { Ws = W5; Wd = wt5; K = 256;  Nn = 128;  off = 3801088; }
        else return;
        long i = idx - off;
        int nn = (int)(i & (Nn - 1));
        int kk = (int)(i >> __builtin_ctz(Nn));
        Wd[(size_t)nn * K + kk] = __float2bfloat16(Ws[i]);
    }
}

// ---------------- CSR build: 3-phase parallel scan (replaces single-block scan)
#define SB 49   // ceil(50000/1024)

__global__ __launch_bounds__(1024)
void scan_part(const int* __restrict__ counts, int* __restrict__ bsum) {
    __shared__ int wsum[16];
    int tid  = threadIdx.x;
    int lane = tid & 63;
    int wv   = tid >> 6;
    int i = blockIdx.x * 1024 + tid;
    int v = (i < N_NODES) ? counts[i] : 0;
#pragma unroll
    for (int off = 32; off > 0; off >>= 1) v += __shfl_down(v, off, 64);
    if (lane == 0) wsum[wv] = v;
    __syncthreads();
    if (wv == 0 && lane < 16) {
        int t = wsum[lane];
#pragma unroll
        for (int off = 8; off > 0; off >>= 1) t += __shfl_down(t, off, 16);
        if (lane == 0) bsum[blockIdx.x] = t;
    }
}

__global__ void scan_mid(const int* __restrict__ bsum, int* __restrict__ boff,
                         int* __restrict__ rowptr) {
    int lane = threadIdx.x;   // 64 threads
    int v = (lane < SB) ? bsum[lane] : 0;
    int s = v;
#pragma unroll
    for (int off = 1; off < 64; off <<= 1) {
        int t = __shfl_up(s, off, 64);
        if (lane >= off) s += t;
    }
    if (lane < SB) boff[lane] = s - v;          // exclusive
    if (lane == 0) rowptr[N_NODES] = N_EDGES;
}

__global__ __launch_bounds__(1024)
void scan_final(const int* __restrict__ counts, const int* __restrict__ boff,
                int* __restrict__ rowptr, int* __restrict__ cursor,
                float* __restrict__ dinv, float* __restrict__ selfw) {
    __shared__ int wsum[16];
    int tid  = threadIdx.x;
    int lane = tid & 63;
    int wv   = tid >> 6;
    int i = blockIdx.x * 1024 + tid;
    int v = (i < N_NODES) ? counts[i] : 0;
    int s = v;
#pragma unroll
    for (int off = 1; off < 64; off <<= 1) {
        int t = __shfl_up(s, off, 64);
        if (lane >= off) s += t;
    }
    if (lane == 63) wsum[wv] = s;
    __syncthreads();
    if (wv == 0 && lane < 16) {
        int t = wsum[lane];
#pragma unroll
        for (int off = 1; off < 16; off <<= 1) {
            int u = __shfl_up(t, off, 64);
            if (lane >= off) t += u;
        }
        wsum[lane] = t;
    }
    __syncthreads();
    int wbase = (wv == 0) ? 0 : wsum[wv - 1];
    if (i < N_NODES) {
        int excl = boff[blockIdx.x] + wbase + s - v;
        rowptr[i] = excl;
        cursor[i] = excl;
        float di = rsqrtf((float)v + 1.0f);     // deg includes self-loop
        dinv[i] = di;
        selfw[i] = di * di;
    }
}

__global__ void fill_kernel(const int* __restrict__ ei, const int* __restrict__ flag,
                            int* __restrict__ cursor, const float* __restrict__ dinv,
                            int* __restrict__ esrc, float* __restrict__ ewt) {
    int e = blockIdx.x * 256 + threadIdx.x;
    if (e < N_EDGES) {
        int is64 = *flag;
        int s = load_edge(ei, 0, e, is64);
        int d = load_edge(ei, 1, e, is64);
        int p = atomicAdd(&cursor[d], 1);
        esrc[p] = s;
        ewt[p]  = dinv[s] * dinv[d];
    }
}

// ---------------- GEMM: C[MP][Nn] = A[MP][K] @ Wt[Nn][K]^T  (FROZEN R7 version)
// bf16 in, fp32 acc, bf16 out. global_load_lds width-16 staging, XOR-swizzled
// LDS (0 bank conflicts, R4), XCD-aware panel swizzle (FETCH 812->192 MB, R5).
// 716 TF = 82% of the m97-structure plateau. R8's producer-consumer rewrite
// regressed (2 producer waves serialize staging; occupancy 29->18%) — reverted.
#define BM 128
#define BN 128
#define BK 64

__device__ __forceinline__ void stage16(const bf16_t* g, bf16_t* l) {
    __builtin_amdgcn_global_load_lds(
        (const __attribute__((address_space(1))) void*)g,
        (__attribute__((address_space(3))) void*)l, 16, 0, 0);
}

__global__ __launch_bounds__(256)
void gemm_bf16(const bf16_t* __restrict__ A, const bf16_t* __restrict__ Bt,
               bf16_t* __restrict__ C, int K, int Nn,
               const float* __restrict__ bias, int relu, int nx, int ny) {
    int id   = blockIdx.x;
    int xcd  = id & 7;
    int slot = id >> 3;
    int y    = (slot / nx) * 8 + xcd;
    int xt   = slot % nx;
    if (y >= ny) return;

    __shared__ __align__(16) bf16_t ldsA[BM * BK];   // 16 KB
    __shared__ __align__(16) bf16_t ldsB[BN * BK];   // 16 KB

    int tid  = threadIdx.x;
    int lane = tid & 63;
    int wave = tid >> 6;
    int m15  = lane & 15;
    int quad = lane >> 4;
    int wm = (wave & 1) * 64;
    int wn = (wave >> 1) * 64;
    long bm0 = (long)y * BM;
    long bn0 = (long)xt * BN;

    floatx4 acc[4][4] = {};

    int rb   = tid >> 3;
    int cole = ((tid & 7) ^ (rb & 7)) * 8;
    const bf16_t* pa = A  + (bm0 + rb) * (long)K + cole;
    const bf16_t* pb = Bt + (bn0 + rb) * (long)K + cole;
    bf16_t* la = ldsA + tid * 8;
    bf16_t* lb = ldsB + tid * 8;
    const long step32 = 32 * (long)K;

    int fx   = lane & 7;
    int blk0 = ((0 + quad) ^ fx) * 8;     // kk = 0
    int blk1 = ((4 + quad) ^ fx) * 8;     // kk = 32
    int rowA = (wm + m15) * BK;
    int rowB = (wn + m15) * BK;

    for (int k0 = 0; k0 < K; k0 += BK) {
#pragma unroll
        for (int it = 0; it < 4; ++it) {
            stage16(pa + it * step32, la + it * 2048);
            stage16(pb + it * step32, lb + it * 2048);
        }
        pa += BK;
        pb += BK;
        __syncthreads();
#pragma unroll
        for (int kk = 0; kk < 2; ++kk) {
            int blk = kk ? blk1 : blk0;
            short8 af[4], bfr[4];
#pragma unroll
            for (int i = 0; i < 4; ++i)
                af[i] = *(const short8*)(&ldsA[rowA + i * (16 * BK) + blk]);
#pragma unroll
            for (int j = 0; j < 4; ++j)
                bfr[j] = *(const short8*)(&ldsB[rowB + j * (16 * BK) + blk]);
#pragma unroll
            for (int i = 0; i < 4; ++i)
#pragma unroll
                for (int j = 0; j < 4; ++j)
                    acc[i][j] = __builtin_amdgcn_mfma_f32_16x16x32_bf16(af[i], bfr[j], acc[i][j], 0, 0, 0);
        }
        __syncthreads();
    }

    // epilogue: D row = quad*4 + r, col = lane&15 (verified m89/m91 layout)
#pragma unroll
    for (int i = 0; i < 4; ++i) {
#pragma unroll
        for (int j = 0; j < 4; ++j) {
            long row0 = bm0 + wm + i * 16 + quad * 4;
            long col  = bn0 + wn + j * 16 + m15;
            float bv = bias ? bias[col] : 0.f;
#pragma unroll
            for (int r = 0; r < 4; ++r) {
                float v = acc[i][j][r] + bv;
                if (relu) v = fmaxf(v, 0.f);
                C[(row0 + r) * (long)Nn + col] = __float2bfloat16(v);
            }
        }
    }
}

// ---------------- aggregation (unchanged from R7) ----------------
__device__ __forceinline__ void unpack8(uint4 v, float* f) {
    uint32_t u[4] = {v.x, v.y, v.z, v.w};
#pragma unroll
    for (int i = 0; i < 4; ++i) {
        f[2 * i]     = __uint_as_float(u[i] << 16);
        f[2 * i + 1] = __uint_as_float(u[i] & 0xffff0000u);
    }
}

__global__ __launch_bounds__(256)
void agg_kernel(const bf16_t* __restrict__ hW, const int* __restrict__ rowptr,
                const int* __restrict__ esrc, const float* __restrict__ ewt,
                const float* __restrict__ selfw,
                const float* __restrict__ bias, bf16_t* __restrict__ outb,
                float* __restrict__ outf, int Nn, int chunks, int npw, int nsh,
                int relu, int rows) {
    int wave = threadIdx.x >> 6;
    int lane = threadIdx.x & 63;
    long unit = (long)blockIdx.x * 4 + wave;
    int n, c0;
    if (npw > 1) {
        int l8 = lane * 8;
        n  = (int)(unit * npw + (l8 >> nsh));
        c0 = l8 & (Nn - 1);
    } else {
        n  = (int)(unit / chunks);
        c0 = (int)(unit % chunks) * 512 + lane * 8;
    }
    if (n >= rows || c0 >= Nn) return;

    if (n >= N_NODES) {                         // zero pad rows (bf16 outputs)
        if (outb) *(uint4*)(outb + (size_t)n * Nn + c0) = make_uint4(0, 0, 0, 0);
        return;
    }

    int r0 = rowptr[n], r1 = rowptr[n + 1];
    float acc[8] = {};

    for (int e = r0; e < r1; e += 4) {
        int e1 = (e + 1 < r1) ? e + 1 : e;
        int e2 = (e + 2 < r1) ? e + 2 : e;
        int e3 = (e + 3 < r1) ? e + 3 : e;
        int s0 = esrc[e], s1 = esrc[e1], s2 = esrc[e2], s3 = esrc[e3];
        float w0 = ewt[e];
        float w1 = (e + 1 < r1) ? ewt[e1] : 0.f;
        float w2 = (e + 2 < r1) ? ewt[e2] : 0.f;
        float w3 = (e + 3 < r1) ? ewt[e3] : 0.f;
        uint4 v0 = *(const uint4*)(hW + (size_t)s0 * Nn + c0);
        uint4 v1 = *(const uint4*)(hW + (size_t)s1 * Nn + c0);
        uint4 v2 = *(const uint4*)(hW + (size_t)s2 * Nn + c0);
        uint4 v3 = *(const uint4*)(hW + (size_t)s3 * Nn + c0);
        float f0[8], f1[8], f2[8], f3[8];
        unpack8(v0, f0); unpack8(v1, f1); unpack8(v2, f2); unpack8(v3, f3);
#pragma unroll
        for (int j = 0; j < 8; ++j)
            acc[j] += f0[j] * w0 + f1[j] * w1 + f2[j] * w2 + f3[j] * w3;
    }

    {   // self-loop
        uint4 v = *(const uint4*)(hW + (size_t)n * Nn + c0);
        float fv[8]; unpack8(v, fv);
        float w = selfw[n];
#pragma unroll
        for (int j = 0; j < 8; ++j) acc[j] += fv[j] * w;
    }
    if (bias) {
#pragma unroll
        for (int j = 0; j < 8; ++j) acc[j] += bias[c0 + j];
    }
    if (relu) {
#pragma unroll
        for (int j = 0; j < 8; ++j) acc[j] = fmaxf(acc[j], 0.f);
    }
    if (outf) {
        *(float4*)(outf + (size_t)n * Nn + c0)     = make_float4(acc[0], acc[1], acc[2], acc[3]);
        *(float4*)(outf + (size_t)n * Nn + c0 + 4) = make_float4(acc[4], acc[5], acc[6], acc[7]);
    } else {
        union { bf16_t h[8]; uint4 u; } o;
#pragma unroll
        for (int j = 0; j < 8; ++j) o.h[j] = __float2bfloat16(acc[j]);
        *(uint4*)(outb + (size_t)n * Nn + c0) = o.u;
    }
}

// ---------------- driver ----------------
extern "C" void kernel_launch(void* const* d_in, const int* in_sizes, int n_in,
                              void* d_out, int out_size, void* d_ws, size_t ws_size,
                              hipStream_t stream) {
    (void)in_sizes; (void)n_in; (void)out_size; (void)ws_size;
    const float* x  = (const float*)d_in[0];
    const int*   ei = (const int*)d_in[1];
    const float* W[5] = {(const float*)d_in[2], (const float*)d_in[4], (const float*)d_in[6],
                         (const float*)d_in[8], (const float*)d_in[10]};
    const float* B[5] = {(const float*)d_in[3], (const float*)d_in[5], (const float*)d_in[7],
                         (const float*)d_in[9], (const float*)d_in[11]};
    static const int dims[6] = {512, 2048, 1024, 512, 256, 128};

    // ---- arena (peak ~320 MB) ----
    const size_t SZ_A = (size_t)MP * 512 * 2;
    const size_t SZ_B = (size_t)MP * 512 * 2;
    const size_t SZ_C = (size_t)MP * 2048 * 2;
    char* base = (char*)d_ws;
    bf16_t* regA = (bf16_t*)base;
    bf16_t* regB = (bf16_t*)(base + SZ_A);
    bf16_t* regC = (bf16_t*)(base + SZ_A + SZ_B);
    char* p = base + SZ_A + SZ_B + SZ_C;
    auto take = [&](size_t bytes) { char* r = p; p += (bytes + 255) & ~(size_t)255; return r; };
    bf16_t* wt[5];
    for (int i = 0; i < 5; ++i) wt[i] = (bf16_t*)take((size_t)dims[i] * dims[i + 1] * 2);
    int*   counts = (int*)take((size_t)N_NODES * 4);
    int*   rowptr = (int*)take((size_t)(N_NODES + 1) * 4);
    int*   cursor = (int*)take((size_t)N_NODES * 4);
    int*   esrc   = (int*)take((size_t)N_EDGES * 4);
    float* ewt    = (float*)take((size_t)N_EDGES * 4);
    float* dinv   = (float*)take((size_t)N_NODES * 4);
    float* selfw  = (float*)take((size_t)N_NODES * 4);
    int*   eflag  = (int*)take(256);
    int*   bsum   = (int*)take((size_t)SB * 4);
    int*   boff   = (int*)take((size_t)SB * 4);

    // ---- preprocessing ----
    detect_kernel<<<1, 64, 0, stream>>>(ei, eflag);
    hipMemsetAsync(counts, 0, (size_t)N_NODES * 4, stream);
    bf16_t* xb = regA;
    preproc_kernel<<<CB + XB + WB, 256, 0, stream>>>(ei, eflag, counts, x, xb,
                                                     W[0], W[1], W[2], W[3], W[4],
                                                     wt[0], wt[1], wt[2], wt[3], wt[4]);
    scan_part<<<SB, 1024, 0, stream>>>(counts, bsum);
    scan_mid<<<1, 64, 0, stream>>>(bsum, boff, rowptr);
    scan_final<<<SB, 1024, 0, stream>>>(counts, boff, rowptr, cursor, dinv, selfw);
    fill_kernel<<<(N_EDGES + 255) / 256, 256, 0, stream>>>(ei, eflag, cursor, dinv, esrc, ewt);

    auto launch_gemm = [&](const bf16_t* a, const bf16_t* bt, bf16_t* c,
                           int K, int Nn, const float* bias, int relu) {
        int nx = Nn / BN;
        int ny = MP / BM;                       // 391
        int blocks = nx * (((ny + 7) / 8) * 8); // pad panel groups to 8 XCDs
        gemm_bf16<<<blocks, 256, 0, stream>>>(a, bt, c, K, Nn, bias, relu, nx, ny);
    };

    auto launch_agg = [&](const bf16_t* hw, const float* bias, bf16_t* outb,
                          float* outf, int Nn, int relu, int rows) {
        int chunks = Nn > 512 ? Nn / 512 : 1;
        int npw    = Nn < 512 ? 512 / Nn : 1;
        int nsh    = 31 - __builtin_clz(Nn);
        long units = (long)((rows + npw - 1) / npw) * chunks;
        int blocks = (int)((units + 3) / 4);
        agg_kernel<<<blocks, 256, 0, stream>>>(hw, rowptr, esrc, ewt, selfw, bias,
                                               outb, outf, Nn, chunks, npw, nsh, relu, rows);
    };

    // ---- layer 1: g1 = A_hat x ; h1 = relu(g1 @ W1 + b1) ----
    bf16_t* g1 = regB;
    bf16_t* h1 = regC;
    launch_agg(xb, nullptr, g1, nullptr, 512, 0, MP);
    launch_gemm(g1, wt[0], h1, 512, 2048, B[0], 1);

    // ---- layers 2..5 ----
    // buffer schedule: hw2->A+B, h2->C, hw3->A, h3->B, hw4->A, h4->B, hw5->A
    bf16_t* hwbuf[4] = {regA, regA, regA, regA};
    bf16_t* hbuf[3]  = {regC, regB, regB};
    const bf16_t* hin = h1;
    for (int l = 1; l < 5; ++l) {
        int K = dims[l], Nn = dims[l + 1];
        bf16_t* hw = hwbuf[l - 1];
        launch_gemm(hin, wt[l], hw, K, Nn, nullptr, 0);
        if (l < 4) {
            bf16_t* hn = hbuf[l - 1];
            launch_agg(hw, B[l], hn, nullptr, Nn, 1, MP);
            hin = hn;
        } else {
            launch_agg(hw, B[l], nullptr, (float*)d_out, Nn, 0, N_NODES);
        }
    }
}